// Round 1
// baseline (588.447 us; speedup 1.0000x reference)
//
#include <hip/hip_runtime.h>
#include <math.h>

// ---- problem constants ----
#define DIMC   128          // model dim / LN width / out channels
#define LTOT   16384        // sequence length = 16*32*32
#define BATCH  2
#define DI     256          // d_inner
#define NST    16           // d_state
#define RNK    8            // dt_rank
#define NCH    256          // scan chunks
#define CH     64           // chunk length  (NCH*CH == LTOT)
#define BL     (BATCH*LTOT) // 32768
#define KC     64           // GEMM K-chunk

__device__ __forceinline__ float sigmoidf_(float x){ return 1.0f/(1.0f+__expf(-x)); }
__device__ __forceinline__ float softplusf_(float x){ return (x>20.0f)? x : log1pf(__expf(x)); }

// ---------------- LayerNorm stats: mean/rstd per (b,l) ----------------
__global__ __launch_bounds__(256) void k_ln_stats(const float* __restrict__ x,
                                                  float* __restrict__ mean,
                                                  float* __restrict__ rstd)
{
    int g = blockIdx.x*256 + threadIdx.x;       // 0..BL-1
    int b = g / LTOT, l = g % LTOT;
    const float* xp = x + (size_t)b*DIMC*LTOT + l;
    float s = 0.f, s2 = 0.f;
#pragma unroll 8
    for (int c = 0; c < DIMC; ++c) {
        float v = xp[(size_t)c*LTOT];
        s += v; s2 += v*v;
    }
    float mu  = s * (1.0f/DIMC);
    float var = s2 * (1.0f/DIMC) - mu*mu;
    mean[g] = mu;
    rstd[g] = rsqrtf(var + 1e-5f);
}

// ---------------- in_proj GEMM with fused LN:  xz = xn @ W.T ----------------
// x:(B,128,L) K-major A; W:(512,128). Output split into xl / z, each (BL,256).
__global__ __launch_bounds__(256) void k_gemm_in(const float* __restrict__ x,
                                                 const float* __restrict__ mean,
                                                 const float* __restrict__ rstd,
                                                 const float* __restrict__ lnw,
                                                 const float* __restrict__ lnb,
                                                 const float* __restrict__ W,
                                                 float* __restrict__ xl,
                                                 float* __restrict__ zz)
{
    __shared__ __align__(16) float As[KC][68];
    __shared__ __align__(16) float Ws[KC][68];
    __shared__ float sm[64], sr[64];
    int tid = threadIdx.x;
    int m0 = blockIdx.x*64;                      // base over BL
    int j0 = blockIdx.y*64;                      // base over 512
    int b = m0 / LTOT, l0 = m0 % LTOT;
    int tl = tid & 15, tw = tid >> 4;
    float acc[4][4];
#pragma unroll
    for (int i=0;i<4;i++) { acc[i][0]=0; acc[i][1]=0; acc[i][2]=0; acc[i][3]=0; }
    if (tid < 64) { sm[tid] = mean[m0+tid]; sr[tid] = rstd[m0+tid]; }

    for (int kc = 0; kc < DIMC; kc += KC) {
        __syncthreads();
#pragma unroll
        for (int i=0;i<16;i++){
            int e = tid + i*256; int cc = e>>6, ll = e&63; int c = kc+cc;
            float v = x[((size_t)b*DIMC + c)*LTOT + l0 + ll];
            As[cc][ll] = (v - sm[ll])*sr[ll]*lnw[c] + lnb[c];
        }
#pragma unroll
        for (int i=0;i<16;i++){
            int e = tid + i*256; int jj = e>>6, cc = e&63;
            Ws[cc][jj] = W[(size_t)(j0+jj)*DIMC + kc+cc];
        }
        __syncthreads();
#pragma unroll 8
        for (int cc=0; cc<KC; cc++){
            float4 a4 = *(const float4*)&As[cc][tl*4];
            float4 w4 = *(const float4*)&Ws[cc][tw*4];
            float av[4] = {a4.x,a4.y,a4.z,a4.w};
            float wv[4] = {w4.x,w4.y,w4.z,w4.w};
#pragma unroll
            for (int li=0;li<4;li++)
#pragma unroll
                for (int ji=0;ji<4;ji++)
                    acc[li][ji] = fmaf(av[li], wv[ji], acc[li][ji]);
        }
    }
#pragma unroll
    for (int li=0;li<4;li++){
        int g = m0 + tl*4 + li;                 // b*L + l
        int j = j0 + tw*4;
        float4 v = make_float4(acc[li][0],acc[li][1],acc[li][2],acc[li][3]);
        if (j < DI) *(float4*)&xl[(size_t)g*DI + j]        = v;
        else        *(float4*)&zz[(size_t)g*DI + (j-DI)]   = v;
    }
}

// ---------------- causal depthwise conv (k=4) + silu, into scan order ----------------
// xs[b, t, d] = silu( sum_k w[d,k] * xl[b, p(t-3+k), d] + cb[d] ),  p(t)=rev? L-1-t : t
__global__ __launch_bounds__(DI) void k_conv(const float* __restrict__ xl,
                                             const float* __restrict__ cw,
                                             const float* __restrict__ cb,
                                             float* __restrict__ xs, int rev)
{
    int d  = threadIdx.x;
    int t0 = blockIdx.x*8;
    int b  = blockIdx.y;
    float4 w4 = ((const float4*)cw)[d];
    float bb = cb[d];
    float r[11];
#pragma unroll
    for (int i=0;i<11;i++){
        int t = t0 - 3 + i;
        if (t < 0) r[i] = 0.f;
        else {
            int p = rev ? (LTOT-1-t) : t;
            r[i] = xl[((size_t)b*LTOT + p)*DI + d];
        }
    }
#pragma unroll
    for (int tt=0;tt<8;tt++){
        float xc = bb + w4.x*r[tt] + w4.y*r[tt+1] + w4.z*r[tt+2] + w4.w*r[tt+3];
        xs[((size_t)b*LTOT + t0+tt)*DI + d] = xc * sigmoidf_(xc);
    }
}

// ---------------- x_proj GEMM: dbl(BL,40) = xs(BL,256) @ W(40,256).T ----------------
__global__ __launch_bounds__(256) void k_xproj(const float* __restrict__ xs,
                                               const float* __restrict__ W,
                                               float* __restrict__ dbl)
{
    __shared__ float Xs[64][65];
    __shared__ float Ws[40][64];
    int tid = threadIdx.x;
    int g0 = blockIdx.x*64;
    int tl = tid & 63, wv = tid >> 6;           // wave wv handles r = wv*10..wv*10+9
    float acc[10];
#pragma unroll
    for (int i=0;i<10;i++) acc[i]=0.f;
    for (int kc=0; kc<DI; kc+=64){
        __syncthreads();
#pragma unroll
        for (int i=0;i<16;i++){
            int e = tid + i*256;
            Xs[e>>6][e&63] = xs[(size_t)(g0 + (e>>6))*DI + kc + (e&63)];
        }
#pragma unroll
        for (int i=0;i<10;i++){
            int e = tid + i*256;                 // 2560 = 40*64 exactly
            Ws[e>>6][e&63] = W[(size_t)(e>>6)*DI + kc + (e&63)];
        }
        __syncthreads();
#pragma unroll 4
        for (int dd=0; dd<64; dd++){
            float a = Xs[tl][dd];
#pragma unroll
            for (int i=0;i<10;i++)
                acc[i] = fmaf(a, Ws[wv*10+i][dd], acc[i]);
        }
    }
#pragma unroll
    for (int i=0;i<10;i++)
        dbl[(size_t)(g0+tl)*40 + wv*10 + i] = acc[i];
}

// ---------------- scan phase 1: per-chunk local scan -> (prod a, h_local) ----------------
__global__ __launch_bounds__(DI) void k_scan1(const float* __restrict__ xs,
                                              const float* __restrict__ dbl,
                                              const float* __restrict__ Alog,
                                              const float* __restrict__ dtw_,
                                              const float* __restrict__ dtb_,
                                              float* __restrict__ csa,
                                              float* __restrict__ csh)
{
    __shared__ __align__(16) float sd[8*40];
    int d = threadIdx.x, ch = blockIdx.x, b = blockIdx.y;
    float An[NST], dtw[RNK];
#pragma unroll
    for (int n=0;n<NST;n++) An[n] = -__expf(Alog[d*NST+n]);
#pragma unroll
    for (int r=0;r<RNK;r++) dtw[r] = dtw_[d*RNK+r];
    float dtb = dtb_[d];
    float h[NST], ap[NST];
#pragma unroll
    for (int n=0;n<NST;n++){ h[n]=0.f; ap[n]=1.f; }
    int gbase = b*LTOT + ch*CH;
    for (int t8=0; t8<CH; t8+=8){
        for (int e=threadIdx.x; e<320; e+=256)
            sd[e] = dbl[(size_t)(gbase+t8)*40 + e];
        __syncthreads();
#pragma unroll
        for (int tt=0;tt<8;tt++){
            int g = gbase + t8 + tt;
            float xv = xs[(size_t)g*DI + d];
            const float4* rp = (const float4*)(sd + tt*40);
            float4 q0 = rp[0], q1 = rp[1];
            float Bv[NST];
            *(float4*)&Bv[0]=rp[2]; *(float4*)&Bv[4]=rp[3]; *(float4*)&Bv[8]=rp[4]; *(float4*)&Bv[12]=rp[5];
            float dl = dtb;
            dl = fmaf(q0.x,dtw[0],dl); dl = fmaf(q0.y,dtw[1],dl); dl = fmaf(q0.z,dtw[2],dl); dl = fmaf(q0.w,dtw[3],dl);
            dl = fmaf(q1.x,dtw[4],dl); dl = fmaf(q1.y,dtw[5],dl); dl = fmaf(q1.z,dtw[6],dl); dl = fmaf(q1.w,dtw[7],dl);
            float dt = softplusf_(dl);
            float dx = dt * xv;
#pragma unroll
            for (int n=0;n<NST;n++){
                float e = __expf(dt*An[n]);
                ap[n] *= e;
                h[n] = fmaf(e, h[n], dx*Bv[n]);
            }
        }
        __syncthreads();
    }
    size_t cbs = ((size_t)(b*NCH+ch)*DI + d)*NST;
#pragma unroll
    for (int n=0;n<NST;n+=4){
        *(float4*)&csa[cbs+n] = make_float4(ap[n],ap[n+1],ap[n+2],ap[n+3]);
        *(float4*)&csh[cbs+n] = make_float4(h[n],h[n+1],h[n+2],h[n+3]);
    }
}

// ---------------- scan phase 2: sequential combine over chunks ----------------
// csh[ch] is replaced in place by the chunk's true initial state.
__global__ __launch_bounds__(256) void k_scanmid(const float* __restrict__ csa,
                                                 float* __restrict__ csh)
{
    int gi = blockIdx.x*256 + threadIdx.x;       // 0 .. B*DI*NST-1 (8192)
    int b  = gi >> 12;                           // / 4096
    int r  = gi & 4095;
    float carry = 0.f;
#pragma unroll 8
    for (int ch=0; ch<NCH; ch++){
        size_t idx = ((size_t)(b*NCH+ch) << 12) + r;
        float a  = csa[idx];
        float hl = csh[idx];
        csh[idx] = carry;
        carry = fmaf(a, carry, hl);
    }
}

// ---------------- scan phase 3: re-scan from true init, fused C-dot + D-skip + z-gate ----------------
__global__ __launch_bounds__(DI) void k_scan3(const float* __restrict__ xs,
                                              const float* __restrict__ dbl,
                                              const float* __restrict__ zz,
                                              const float* __restrict__ Alog,
                                              const float* __restrict__ dtw_,
                                              const float* __restrict__ dtb_,
                                              const float* __restrict__ Dp,
                                              const float* __restrict__ csh,
                                              float* __restrict__ yacc,
                                              int rev, int accumulate)
{
    __shared__ __align__(16) float sd[8*40];
    int d = threadIdx.x, ch = blockIdx.x, b = blockIdx.y;
    float An[NST], dtw[RNK];
#pragma unroll
    for (int n=0;n<NST;n++) An[n] = -__expf(Alog[d*NST+n]);
#pragma unroll
    for (int r=0;r<RNK;r++) dtw[r] = dtw_[d*RNK+r];
    float dtb = dtb_[d];
    float Dd  = Dp[d];
    float h[NST];
    size_t cbs = ((size_t)(b*NCH+ch)*DI + d)*NST;
#pragma unroll
    for (int n=0;n<NST;n+=4){
        float4 v = *(const float4*)&csh[cbs+n];
        h[n]=v.x; h[n+1]=v.y; h[n+2]=v.z; h[n+3]=v.w;
    }
    int gbase = b*LTOT + ch*CH;
    for (int t8=0; t8<CH; t8+=8){
        for (int e=threadIdx.x; e<320; e+=256)
            sd[e] = dbl[(size_t)(gbase+t8)*40 + e];
        __syncthreads();
#pragma unroll
        for (int tt=0;tt<8;tt++){
            int t = ch*CH + t8 + tt;
            int g = gbase + t8 + tt;
            float xv = xs[(size_t)g*DI + d];
            const float4* rp = (const float4*)(sd + tt*40);
            float4 q0 = rp[0], q1 = rp[1];
            float Bv[NST], Cv[NST];
            *(float4*)&Bv[0]=rp[2]; *(float4*)&Bv[4]=rp[3]; *(float4*)&Bv[8]=rp[4]; *(float4*)&Bv[12]=rp[5];
            *(float4*)&Cv[0]=rp[6]; *(float4*)&Cv[4]=rp[7]; *(float4*)&Cv[8]=rp[8]; *(float4*)&Cv[12]=rp[9];
            float dl = dtb;
            dl = fmaf(q0.x,dtw[0],dl); dl = fmaf(q0.y,dtw[1],dl); dl = fmaf(q0.z,dtw[2],dl); dl = fmaf(q0.w,dtw[3],dl);
            dl = fmaf(q1.x,dtw[4],dl); dl = fmaf(q1.y,dtw[5],dl); dl = fmaf(q1.z,dtw[6],dl); dl = fmaf(q1.w,dtw[7],dl);
            float dt = softplusf_(dl);
            float dx = dt * xv;
            float y = 0.f;
#pragma unroll
            for (int n=0;n<NST;n++){
                float e = __expf(dt*An[n]);
                h[n] = fmaf(e, h[n], dx*Bv[n]);
                y = fmaf(h[n], Cv[n], y);
            }
            y = fmaf(Dd, xv, y);
            int p = rev ? (LTOT-1-t) : t;
            size_t oi = ((size_t)b*LTOT + p)*DI + d;
            float zv = zz[oi];
            float yb = y * (zv * sigmoidf_(zv));
            if (accumulate) yacc[oi] += yb;
            else            yacc[oi]  = yb;
        }
        __syncthreads();
    }
}

// ---------------- out_proj GEMM: out(b,co,p) = sum_d yacc(b,p,d) * W(co,d) ----------------
__global__ __launch_bounds__(256) void k_gemm_out(const float* __restrict__ yacc,
                                                  const float* __restrict__ W,
                                                  float* __restrict__ out)
{
    __shared__ __align__(16) float As[KC][68];   // [dd][pp]
    __shared__ __align__(16) float Ws[KC][68];   // [dd][cc]
    int tid = threadIdx.x;
    int m0 = blockIdx.x*64;                      // p-tile over BL
    int c0 = blockIdx.y*64;                      // co-tile over 128
    int b = m0 / LTOT, p0 = m0 % LTOT;
    int tp = tid & 15, tw = tid >> 4;
    float acc[4][4];
#pragma unroll
    for (int i=0;i<4;i++){ acc[i][0]=0; acc[i][1]=0; acc[i][2]=0; acc[i][3]=0; }
    for (int kc=0; kc<DI; kc+=KC){
        __syncthreads();
#pragma unroll
        for (int i=0;i<16;i++){
            int e = tid + i*256; int pp = e>>6, dd = e&63;
            As[dd][pp] = yacc[(size_t)(m0+pp)*DI + kc+dd];
        }
#pragma unroll
        for (int i=0;i<16;i++){
            int e = tid + i*256; int cc = e>>6, dd = e&63;
            Ws[dd][cc] = W[(size_t)(c0+cc)*DI + kc+dd];
        }
        __syncthreads();
#pragma unroll 8
        for (int dd=0; dd<KC; dd++){
            float4 a4 = *(const float4*)&As[dd][tp*4];
            float4 w4 = *(const float4*)&Ws[dd][tw*4];
            float av[4] = {a4.x,a4.y,a4.z,a4.w};
            float wv[4] = {w4.x,w4.y,w4.z,w4.w};
#pragma unroll
            for (int ci=0;ci<4;ci++)
#pragma unroll
                for (int pi=0;pi<4;pi++)
                    acc[ci][pi] = fmaf(wv[ci], av[pi], acc[ci][pi]);
        }
    }
#pragma unroll
    for (int ci=0;ci<4;ci++){
        int co = c0 + tw*4 + ci;
        float4 v = make_float4(acc[ci][0],acc[ci][1],acc[ci][2],acc[ci][3]);
        *(float4*)&out[((size_t)b*DIMC + co)*LTOT + p0 + tp*4] = v;
    }
}

extern "C" void kernel_launch(void* const* d_in, const int* in_sizes, int n_in,
                              void* d_out, int out_size, void* d_ws, size_t ws_size,
                              hipStream_t stream)
{
    (void)in_sizes; (void)n_in; (void)out_size; (void)ws_size;
    const float* x    = (const float*)d_in[0];
    const float* lnw  = (const float*)d_in[1];
    const float* lnb  = (const float*)d_in[2];
    const float* inW  = (const float*)d_in[3];
    const float* outW = (const float*)d_in[4];
    const float* cw[2]   = {(const float*)d_in[5],  (const float*)d_in[12]};
    const float* cb[2]   = {(const float*)d_in[6],  (const float*)d_in[13]};
    const float* xpW[2]  = {(const float*)d_in[7],  (const float*)d_in[14]};
    const float* dtW[2]  = {(const float*)d_in[8],  (const float*)d_in[15]};
    const float* dtB[2]  = {(const float*)d_in[9],  (const float*)d_in[16]};
    const float* Alog[2] = {(const float*)d_in[10], (const float*)d_in[17]};
    const float* Dp[2]   = {(const float*)d_in[11], (const float*)d_in[18]};
    float* out = (float*)d_out;

    float* w = (float*)d_ws;
    float* mean = w;  w += BL;
    float* rstd = w;  w += BL;
    float* xl   = w;  w += (size_t)BL*DI;
    float* zz   = w;  w += (size_t)BL*DI;
    float* yacc = w;  w += (size_t)BL*DI;
    float* xs   = w;  w += (size_t)BL*DI;
    float* dbl  = w;  w += (size_t)BL*40;
    float* csa  = w;  w += (size_t)BATCH*NCH*DI*NST;
    float* csh  = w;  w += (size_t)BATCH*NCH*DI*NST;

    k_ln_stats<<<BL/256, 256, 0, stream>>>(x, mean, rstd);
    k_gemm_in<<<dim3(BL/64, 8), 256, 0, stream>>>(x, mean, rstd, lnw, lnb, inW, xl, zz);
    for (int dir=0; dir<2; dir++){
        k_conv  <<<dim3(LTOT/8, BATCH), DI, 0, stream>>>(xl, cw[dir], cb[dir], xs, dir);
        k_xproj <<<BL/64, 256, 0, stream>>>(xs, xpW[dir], dbl);
        k_scan1 <<<dim3(NCH, BATCH), DI, 0, stream>>>(xs, dbl, Alog[dir], dtW[dir], dtB[dir], csa, csh);
        k_scanmid<<<(BATCH*DI*NST)/256, 256, 0, stream>>>(csa, csh);
        k_scan3 <<<dim3(NCH, BATCH), DI, 0, stream>>>(xs, dbl, zz, Alog[dir], dtW[dir], dtB[dir],
                                                      Dp[dir], csh, yacc, dir, dir);
    }
    k_gemm_out<<<dim3(BL/64, DIMC/64), 256, 0, stream>>>(yacc, outW, out);
}